// Round 1
// baseline (128.894 us; speedup 1.0000x reference)
//
#include <hip/hip_runtime.h>
#include <math.h>

#define BDIM 8
#define NDIM 128
#define TDIM 1024
#define TPB 256

#define EPS_F 1e-12f
#define RHO_LIM_F (1.0f - 1e-6f)
#define PI_F 3.14159265358979323846f

__global__ __launch_bounds__(TPB) void conv_arccos_kernel(
    const float* __restrict__ k,      // (B,B,N,T,2)
    const float* __restrict__ leak,   // scalar
    const float* __restrict__ alpha,  // (3,)
    const float* __restrict__ beta,   // scalar
    float* __restrict__ out)          // (B,B,N,T,2)
{
    __shared__ float sc0[TDIM + 2];
    __shared__ float scn[TDIM + 2];

    const int row = blockIdx.x;           // 0 .. B*B*N-1
    const int n   = row % NDIM;
    const int bb  = row / NDIM;
    const int b2  = bb % BDIM;
    const int b1  = bb / BDIM;

    const int tid = threadIdx.x;

    // forward value of clamp_pg(x) is max(x, 0)
    const float a   = fmaxf(leak[0], 0.0f);
    const float w0  = fmaxf(alpha[0], 0.0f);
    const float w1  = fmaxf(alpha[1], 0.0f);
    const float w2  = fmaxf(alpha[2], 0.0f);
    const float bia = fmaxf(beta[0], 0.0f);

    const float one_m  = (1.0f - a) * (1.0f - a);
    const float coef   = 1.0f + a * a;
    const float inv2pi = 1.0f / (2.0f * PI_F);

    const float2* krow   = (const float2*)(k) + (size_t)row * TDIM;
    // v[b, t] = k[b, b, 0, t, 0]  -> float2 index ((b*B+b)*N)*T + t, .x component
    const float2* vrow_x = (const float2*)(k) + (size_t)(b1 * BDIM + b1) * NDIM * TDIM;
    const float2* vrow_y = (const float2*)(k) + (size_t)(b2 * BDIM + b2) * NDIM * TDIM;

    // zero conv halo
    if (tid == 0) {
        sc0[0] = 0.0f; scn[0] = 0.0f;
        sc0[TDIM + 1] = 0.0f; scn[TDIM + 1] = 0.0f;
    }

    #pragma unroll
    for (int j = 0; j < TDIM / TPB; ++j) {
        const int t = tid + j * TPB;
        float2 kv = krow[t];
        const float kgp  = kv.x;
        const float kntk = kv.y;

        const float vx = vrow_x[t].x;
        const int   ty = n + t;
        const float vy = (ty < TDIM) ? vrow_y[ty].x : 0.0f;

        const float sx   = sqrtf(fmaxf(vx, 0.0f));
        const float sy   = sqrtf(fmaxf(vy, 0.0f));
        const float prod = sx * sy;
        const float den  = fmaxf(prod, EPS_F);

        const float rho   = fminf(fmaxf(kgp / den, -RHO_LIM_F), RHO_LIM_F);
        const float theta = acosf(rho);
        const float s     = sqrtf(1.0f - rho * rho);

        const float br = coef * PI_F - one_m * theta;   // coef*pi - one_m*theta
        const float c0 = prod * inv2pi * (one_m * s + rho * br);
        const float c1 = br * inv2pi;

        sc0[t + 1] = c0;
        scn[t + 1] = c1 * kntk;
    }

    __syncthreads();

    float2* orow = (float2*)(out) + (size_t)row * TDIM;
    #pragma unroll
    for (int j = 0; j < TDIM / TPB; ++j) {
        const int t = tid + j * TPB;
        const float kg = w0 * sc0[t] + w1 * sc0[t + 1] + w2 * sc0[t + 2];
        const float kn = w0 * scn[t] + w1 * scn[t + 1] + w2 * scn[t + 2] + kg;
        float2 o;
        o.x = kg + bia;
        o.y = kn + bia;
        orow[t] = o;
    }
}

extern "C" void kernel_launch(void* const* d_in, const int* in_sizes, int n_in,
                              void* d_out, int out_size, void* d_ws, size_t ws_size,
                              hipStream_t stream) {
    const float* k     = (const float*)d_in[0];
    const float* leak  = (const float*)d_in[1];
    const float* alpha = (const float*)d_in[2];
    const float* beta  = (const float*)d_in[3];
    float* out = (float*)d_out;

    const int n_rows = BDIM * BDIM * NDIM;   // 8192
    conv_arccos_kernel<<<n_rows, TPB, 0, stream>>>(k, leak, alpha, beta, out);
}

// Round 2
// 123.431 us; speedup vs baseline: 1.0443x; 1.0443x over previous
//
#include <hip/hip_runtime.h>
#include <math.h>

#define BDIM 8
#define NDIM 128
#define TDIM 1024
#define TPB 256

#define EPS_F 1e-12f
#define RHO_LIM_F (1.0f - 1e-6f)
#define PI_F 3.14159265358979323846f

// Layout: per block (one (b1,b2,n) row of T=1024):
//   phase 1 computes c0[t], cn[t]=c1[t]*k_ntk[t] into LDS at index t+2
//   (left halo at idx 1, right halo at idx 1026, both zero; +2 offset keeps
//   the paired stores 8B-aligned since t is even per thread)
//   phase 2 does the 3-tap conv and writes float4 {kg0,kn0,kg1,kn1}.

__global__ __launch_bounds__(TPB) void conv_arccos_kernel(
    const float* __restrict__ k,      // (B,B,N,T,2)
    const float* __restrict__ leak,   // scalar
    const float* __restrict__ alpha,  // (3,)
    const float* __restrict__ beta,   // scalar
    float* __restrict__ out)          // (B,B,N,T,2)
{
    __shared__ float sc0[TDIM + 4];
    __shared__ float scn[TDIM + 4];

    const int row = blockIdx.x;           // 0 .. B*B*N-1
    const int n   = row % NDIM;
    const int bb  = row / NDIM;
    const int b2  = bb % BDIM;
    const int b1  = bb / BDIM;
    const int tid = threadIdx.x;

    // forward value of clamp_pg(x) is max(x, 0)
    const float a   = fmaxf(leak[0], 0.0f);
    const float w0  = fmaxf(alpha[0], 0.0f);
    const float w1  = fmaxf(alpha[1], 0.0f);
    const float w2  = fmaxf(alpha[2], 0.0f);
    const float bia = fmaxf(beta[0], 0.0f);

    const float one_m  = (1.0f - a) * (1.0f - a);
    const float coef   = 1.0f + a * a;
    const float inv2pi = 0.15915494309189535f;

    const float4* krow4 = (const float4*)(k + (size_t)row * TDIM * 2);
    // v[b, t] = k[b, b, 0, t, 0]
    const float2* vrx = (const float2*)(k) + (size_t)(b1 * BDIM + b1) * NDIM * TDIM;
    const float2* vry = (const float2*)(k) + (size_t)(b2 * BDIM + b2) * NDIM * TDIM;

    // zero conv halo: indices 1 (left) and TDIM+2 (right); 0 / TDIM+3 unused
    if (tid < 2) {
        sc0[tid] = 0.0f;            scn[tid] = 0.0f;
        sc0[TDIM + 2 + tid] = 0.0f; scn[TDIM + 2 + tid] = 0.0f;
    }

    if (one_m == 0.0f) {
        // FAST PATH (exact when (1-a)^2 == 0): theta/s terms vanish.
        // c0 = prod * rho * coef/2 ;  c1 = coef/2
        const float hc = 0.5f * coef;
        #pragma unroll
        for (int j = 0; j < TDIM / (2 * TPB); ++j) {
            const int f = tid + j * TPB;   // float4 index (2 elements)
            const int t = 2 * f;
            const float4 kv  = krow4[f];                    // kgp0,kntk0,kgp1,kntk1
            const float4 vx2 = ((const float4*)vrx)[f];     // vx0,-,vx1,-
            const float vy0 = (n + t     < TDIM) ? vry[n + t    ].x : 0.0f;
            const float vy1 = (n + t + 1 < TDIM) ? vry[n + t + 1].x : 0.0f;

            const float p0 = sqrtf(fmaxf(vx2.x, 0.0f) * fmaxf(vy0, 0.0f));
            const float p1 = sqrtf(fmaxf(vx2.z, 0.0f) * fmaxf(vy1, 0.0f));
            const float r0 = fminf(fmaxf(kv.x * __builtin_amdgcn_rcpf(fmaxf(p0, EPS_F)), -RHO_LIM_F), RHO_LIM_F);
            const float r1 = fminf(fmaxf(kv.z * __builtin_amdgcn_rcpf(fmaxf(p1, EPS_F)), -RHO_LIM_F), RHO_LIM_F);

            sc0[t + 2] = p0 * r0 * hc;
            sc0[t + 3] = p1 * r1 * hc;
            scn[t + 2] = hc * kv.y;
            scn[t + 3] = hc * kv.w;
        }
    } else {
        // GENERAL PATH
        #pragma unroll
        for (int j = 0; j < TDIM / (2 * TPB); ++j) {
            const int f = tid + j * TPB;
            const int t = 2 * f;
            const float4 kv  = krow4[f];
            const float4 vx2 = ((const float4*)vrx)[f];
            const float vy0 = (n + t     < TDIM) ? vry[n + t    ].x : 0.0f;
            const float vy1 = (n + t + 1 < TDIM) ? vry[n + t + 1].x : 0.0f;

            const float p0 = sqrtf(fmaxf(vx2.x, 0.0f) * fmaxf(vy0, 0.0f));
            const float p1 = sqrtf(fmaxf(vx2.z, 0.0f) * fmaxf(vy1, 0.0f));
            const float r0 = fminf(fmaxf(kv.x * __builtin_amdgcn_rcpf(fmaxf(p0, EPS_F)), -RHO_LIM_F), RHO_LIM_F);
            const float r1 = fminf(fmaxf(kv.z * __builtin_amdgcn_rcpf(fmaxf(p1, EPS_F)), -RHO_LIM_F), RHO_LIM_F);

            const float th0 = acosf(r0);
            const float th1 = acosf(r1);
            const float s0  = sqrtf(1.0f - r0 * r0);
            const float s1  = sqrtf(1.0f - r1 * r1);
            const float br0 = coef * PI_F - one_m * th0;
            const float br1 = coef * PI_F - one_m * th1;

            sc0[t + 2] = p0 * inv2pi * (one_m * s0 + r0 * br0);
            sc0[t + 3] = p1 * inv2pi * (one_m * s1 + r1 * br1);
            scn[t + 2] = br0 * inv2pi * kv.y;
            scn[t + 3] = br1 * inv2pi * kv.w;
        }
    }

    __syncthreads();

    float4* orow = (float4*)(out + (size_t)row * TDIM * 2);
    #pragma unroll
    for (int j = 0; j < TDIM / (2 * TPB); ++j) {
        const int f = tid + j * TPB;
        const int t = 2 * f;
        const float c0l = sc0[t + 1], c00 = sc0[t + 2], c01 = sc0[t + 3], c0r = sc0[t + 4];
        const float cnl = scn[t + 1], cn0 = scn[t + 2], cn1 = scn[t + 3], cnr = scn[t + 4];

        const float kg0 = w0 * c0l + w1 * c00 + w2 * c01;
        const float kg1 = w0 * c00 + w1 * c01 + w2 * c0r;
        const float kn0 = w0 * cnl + w1 * cn0 + w2 * cn1 + kg0;
        const float kn1 = w0 * cn0 + w1 * cn1 + w2 * cnr + kg1;

        float4 o;
        o.x = kg0 + bia;
        o.y = kn0 + bia;
        o.z = kg1 + bia;
        o.w = kn1 + bia;
        orow[f] = o;
    }
}

extern "C" void kernel_launch(void* const* d_in, const int* in_sizes, int n_in,
                              void* d_out, int out_size, void* d_ws, size_t ws_size,
                              hipStream_t stream) {
    const float* k     = (const float*)d_in[0];
    const float* leak  = (const float*)d_in[1];
    const float* alpha = (const float*)d_in[2];
    const float* beta  = (const float*)d_in[3];
    float* out = (float*)d_out;

    const int n_rows = BDIM * BDIM * NDIM;   // 8192
    conv_arccos_kernel<<<n_rows, TPB, 0, stream>>>(k, leak, alpha, beta, out);
}